// Round 5
// baseline (255.117 us; speedup 1.0000x reference)
//
#include <hip/hip_runtime.h>

// Octree cross-entropy loss.
// D=256, BS=16 -> 4096 level-0 blocks of 16^3 voxels.
// Level 0 loss = sum_blocks mean_voxels(nll) = (sum over ALL voxels)/4096.
// Levels 1..4 (b = 32,64,128,256): 3-class CE (pure0/pure1/mixed) * b^3,
// class from per-16^3-block popcounts aggregated upward.
//
// R4 -> R5 changes:
//  - level0: fill-kernel structure. One WAVE per x-plane (65536 waves,
//    4096x1024 grid), 3 independent vector loads/thread, shuffle reduce,
//    write own slot, RETIRE. No __syncthreads/LDS/atomics/loops. R1-R4 all
//    plateaued at ~78 us / 2.6 TB/s because long-lived waves had their loads
//    serialized (compiler) or convoyed (barriers); fillBufferAligned proves
//    6.9 TB/s is reachable via wave turnover (short waves, continuous fresh
//    requests). 8 turnover rounds over the 8192 wave slots.
//  - levels_kernel now also reduces the 65536-slot partial/count arrays
//    (512 KB from L2, ~3 us).
//  - d_ws usage: 65536 floats + 65536 ints = 512 KB.

__device__ __forceinline__ float softplus(float x) {
    // log(1 + e^x), stable
    return fmaxf(x, 0.f) + __logf(1.f + __expf(-fabsf(x)));
}

__device__ __forceinline__ float nll3(const float* __restrict__ l, int c) {
    float a = l[0], b = l[1], d = l[2];
    float m = fmaxf(fmaxf(a, b), d);
    float lse = m + __logf(__expf(a - m) + __expf(b - m) + __expf(d - m));
    return lse - l[c];
}

// 4096 blocks x 1024 threads. Wave w-of-block = x-plane w of octree block
// blockIdx.x. Each thread: 4 voxels (int4 gt + 2x float4 logits).
__global__ __launch_bounds__(1024) void level0_kernel(
    const int* __restrict__ gt,        // [256^3], values +-1, x-major (x,y,z)
    const float* __restrict__ logits,  // [4096, 2, 4096]
    float* __restrict__ partial16,     // [4096*16] per-wave NLL sums
    int* __restrict__ cnt16)           // [4096*16] per-wave popcounts
{
    const int blk  = blockIdx.x;             // (bx*16 + by)*16 + bz
    const int x    = threadIdx.x >> 6;       // x-plane 0..15
    const int lane = threadIdx.x & 63;
    const int bx = blk >> 8;
    const int by = (blk >> 4) & 15;
    const int bz = blk & 15;

    const int iy  = lane >> 2;               // 0..15
    const int izb = (lane & 3) << 2;         // 0,4,8,12

    const int gidx = ((bx * 16 + x) << 16) + ((by * 16 + iy) << 8)
                   + (bz * 16 + izb);
    const int v    = (x << 8) + (lane << 2); // within-block voxel index
    const float* lg = logits + (size_t)blk * 8192;

    const int4   g = *reinterpret_cast<const int4*>(gt + gidx);
    const float4 a = *reinterpret_cast<const float4*>(lg + v);
    const float4 b = *reinterpret_cast<const float4*>(lg + 4096 + v);

    const float dx = a.x - b.x;
    const float dy = a.y - b.y;
    const float dz = a.z - b.z;
    const float dw = a.w - b.w;
    const int t0 = g.x > 0, t1 = g.y > 0, t2 = g.z > 0, t3 = g.w > 0;
    int   ones = t0 + t1 + t2 + t3;
    // target=1 -> nll = softplus(l0-l1); target=0 -> softplus(-(l0-l1))
    float lsum = softplus(t0 ? dx : -dx)
               + softplus(t1 ? dy : -dy)
               + softplus(t2 ? dz : -dz)
               + softplus(t3 ? dw : -dw);

#pragma unroll
    for (int s = 32; s > 0; s >>= 1) {
        lsum += __shfl_down(lsum, s, 64);
        ones += __shfl_down(ones, s, 64);
    }
    if (lane == 0) {
        partial16[(blk << 4) + x] = lsum;
        cnt16[(blk << 4) + x]     = ones;
    }
}

// Single block, 512 threads: reduce per-wave partials, rebuild per-l0-block
// counts in LDS, hierarchical aggregation + 3-class CE for levels 1..4.
__global__ __launch_bounds__(512) void levels_kernel(
    const float* __restrict__ partial16, // [65536]
    const int* __restrict__ cnt16,       // [65536]
    const float* __restrict__ l1,        // [512,3]
    const float* __restrict__ l2,        // [64,3]
    const float* __restrict__ l3,        // [8,3]
    const float* __restrict__ l4,        // [1,3]
    float* __restrict__ out)
{
    __shared__ int   c0[4096];           // per-l0-block popcounts
    __shared__ int   s1[512];
    __shared__ int   s2[64];
    __shared__ int   s3[8];
    __shared__ float red[512];
    const int tid = threadIdx.x;
    float contrib = 0.f;

    // ---- level-0 loss: 65536 partial sums, coalesced float4 reads ----
    {
        float s = 0.f;
#pragma unroll
        for (int i = 0; i < 32; ++i) {
            const float4 p = *reinterpret_cast<const float4*>(
                partial16 + (((i << 9) + tid) << 2));
            s += (p.x + p.y) + (p.z + p.w);
        }
        contrib += s * (1.0f / 4096.0f);     // per-block mean, summed
    }

    // ---- per-l0-block counts: thread tid sums blocks tid*8 .. tid*8+7 ----
    {
#pragma unroll
        for (int j = 0; j < 8; ++j) {
            const int b = (tid << 3) + j;
            const int4* p = reinterpret_cast<const int4*>(cnt16 + (b << 4));
            const int4 c0v = p[0], c1v = p[1], c2v = p[2], c3v = p[3];
            c0[b] = ((c0v.x + c0v.y + c0v.z + c0v.w)
                   + (c1v.x + c1v.y + c1v.z + c1v.w))
                  + ((c2v.x + c2v.y + c2v.z + c2v.w)
                   + (c3v.x + c3v.y + c3v.z + c3v.w));
        }
    }
    __syncthreads();

    // ---- level 1: 8^3 blocks, each aggregates 2^3 level-0 blocks ----
    {
        const int X = tid >> 6, Y = (tid >> 3) & 7, Z = tid & 7;
        int s = 0;
#pragma unroll
        for (int dx = 0; dx < 2; ++dx)
#pragma unroll
            for (int dy = 0; dy < 2; ++dy)
#pragma unroll
                for (int dz = 0; dz < 2; ++dz)
                    s += c0[((X * 2 + dx) * 16 + (Y * 2 + dy)) * 16 + (Z * 2 + dz)];
        s1[tid] = s;
        const int tot = 8 * 4096;
        const int c = (s == 0) ? 0 : ((s == tot) ? 1 : 2);
        contrib += nll3(l1 + tid * 3, c) * 32768.0f;      // 32^3
    }
    __syncthreads();
    // ---- level 2: 4^3 blocks from 8^3 grid ----
    if (tid < 64) {
        const int X = tid >> 4, Y = (tid >> 2) & 3, Z = tid & 3;
        int s = 0;
#pragma unroll
        for (int dx = 0; dx < 2; ++dx)
#pragma unroll
            for (int dy = 0; dy < 2; ++dy)
#pragma unroll
                for (int dz = 0; dz < 2; ++dz)
                    s += s1[((X * 2 + dx) * 8 + (Y * 2 + dy)) * 8 + (Z * 2 + dz)];
        s2[tid] = s;
        const int tot = 64 * 4096;
        const int c = (s == 0) ? 0 : ((s == tot) ? 1 : 2);
        contrib += nll3(l2 + tid * 3, c) * 262144.0f;     // 64^3
    }
    __syncthreads();
    // ---- level 3: 2^3 blocks from 4^3 grid ----
    if (tid < 8) {
        const int X = tid >> 2, Y = (tid >> 1) & 1, Z = tid & 1;
        int s = 0;
#pragma unroll
        for (int dx = 0; dx < 2; ++dx)
#pragma unroll
            for (int dy = 0; dy < 2; ++dy)
#pragma unroll
                for (int dz = 0; dz < 2; ++dz)
                    s += s2[((X * 2 + dx) * 4 + (Y * 2 + dy)) * 4 + (Z * 2 + dz)];
        s3[tid] = s;
        const int tot = 512 * 4096;
        const int c = (s == 0) ? 0 : ((s == tot) ? 1 : 2);
        contrib += nll3(l3 + tid * 3, c) * 2097152.0f;    // 128^3
    }
    __syncthreads();
    // ---- level 4: 1 block = everything ----
    if (tid == 0) {
        int s = 0;
#pragma unroll
        for (int i = 0; i < 8; ++i) s += s3[i];
        const int tot = 4096 * 4096;
        const int c = (s == 0) ? 0 : ((s == tot) ? 1 : 2);
        contrib += nll3(l4, c) * 16777216.0f;             // 256^3
    }

    red[tid] = contrib;
    __syncthreads();
#pragma unroll
    for (int s = 256; s > 0; s >>= 1) {
        if (tid < s) red[tid] += red[tid + s];
        __syncthreads();
    }
    if (tid == 0) out[0] = red[0];
}

extern "C" void kernel_launch(void* const* d_in, const int* in_sizes, int n_in,
                              void* d_out, int out_size, void* d_ws, size_t ws_size,
                              hipStream_t stream) {
    const int*   gt    = (const int*)d_in[0];
    const float* dense = (const float*)d_in[1];
    const float* l1    = (const float*)d_in[2];
    const float* l2    = (const float*)d_in[3];
    const float* l3    = (const float*)d_in[4];
    const float* l4    = (const float*)d_in[5];
    float* out = (float*)d_out;

    float* partial16 = (float*)d_ws;               // 65536 floats (256 KB)
    int*   cnt16     = (int*)(partial16 + 65536);  // 65536 ints  (256 KB)

    level0_kernel<<<4096, 1024, 0, stream>>>(gt, dense, partial16, cnt16);
    levels_kernel<<<1, 512, 0, stream>>>(partial16, cnt16, l1, l2, l3, l4, out);
}